// Round 22
// baseline (92.459 us; speedup 1.0000x reference)
//
#include <hip/hip_runtime.h>
#include <hip/hip_bf16.h>
#include <stdint.h>
#include <stddef.h>

typedef __attribute__((ext_vector_type(8))) short short8;
typedef __attribute__((ext_vector_type(4))) float f32x4;
typedef __attribute__((ext_vector_type(16))) float f32x16;
typedef __attribute__((ext_vector_type(4))) unsigned int uint4v;

#define MFMA16(a, b, c) __builtin_amdgcn_mfma_f32_16x16x32_bf16((a), (b), (c), 0, 0, 0)
#define MFMA32(a, b, c) __builtin_amdgcn_mfma_f32_32x32x16_bf16((a), (b), (c), 0, 0, 0)

__device__ __forceinline__ unsigned short f2bf(float f) {
  unsigned int u = __builtin_bit_cast(unsigned int, f);
  u += 0x7fffu + ((u >> 16) & 1u);
  return (unsigned short)(u >> 16);
}

// validated integer RNE pack — cold paths
__device__ __forceinline__ unsigned int pk2(float lo, float hi) {
  return (unsigned int)f2bf(lo) | ((unsigned int)f2bf(hi) << 16);
}

// hot-path pack: official intrinsic -> compiler-emitted v_cvt_pk_bf16_f32
__device__ __forceinline__ unsigned int pkc(float lo, float hi) {
  __hip_bfloat162 h = __float22bfloat162_rn(make_float2(lo, hi));
  unsigned int u;
  __builtin_memcpy(&u, &h, 4);
  return u;
}

__device__ __forceinline__ short8 mk8(const unsigned short* p) {
  return *(const short8*)p;
}

__device__ __forceinline__ f32x16 zero16() {
  f32x16 v;
#pragma unroll
  for (int i = 0; i < 16; ++i) v[i] = 0.f;
  return v;
}

// swizzled offset into a [rows][40]-half LDS tile holding 32 data cols.
__device__ __forceinline__ int swz40(int row, int c) {
  return row * 40 + ((((c >> 3) ^ (row >> 3)) & 3) << 3) + (c & 7);
}

// ---------------- kernel 0: pack weights into A-fragment-linear bf16 ----------------
__global__ __launch_bounds__(256) void k_prep(const float* __restrict__ wq,
                                              const float* __restrict__ wo,
                                              unsigned short* __restrict__ wq_fl,
                                              unsigned short* __restrict__ wo_fl) {
  int i = blockIdx.x * 256 + threadIdx.x;
  if (i < 98304) {
    int slot = i & 7, lane = (i >> 3) & 63, cch = (i >> 9) & 7, otile = i >> 12;
    int o = otile * 16 + (lane & 15);
    int c = cch * 32 + ((lane >> 4) & 3) * 8 + slot;
    wq_fl[i] = f2bf(wq[o * 256 + c]);
  }
  if (i < 32768) {
    int slot = i & 7, lane = (i >> 3) & 63, cch = (i >> 9) & 3, cotile = i >> 11;
    int co = cotile * 16 + (lane & 15);
    int c = cch * 32 + (lane >> 4) * 8 + slot;
    wo_fl[i] = f2bf(wo[co * 128 + c]);
  }
}

// ---------------- kernel 1: fused RMSNorm + QKV GEMM (r20, unchanged) ----------------
__global__ __launch_bounds__(256) void k_qkv(const float* __restrict__ x,
                                             const float* __restrict__ g,
                                             const unsigned short* __restrict__ wq_fl,
                                             unsigned short* __restrict__ qbuf,
                                             unsigned short* __restrict__ kbuf,
                                             unsigned short* __restrict__ vbuf) {
  int bid = blockIdx.x;            // 1536 = 4b * 6ot * 64pt
  int b = bid / 384;
  int rem = bid % 384;
  int ot = rem / 64;
  int pt = rem % 64;
  int o0 = ot * 64, p0 = pt * 64;

  __shared__ unsigned short xnT[2][64 * 40];
  __shared__ float sqv[16][64];
  __shared__ float rl[64];

  int t = threadIdx.x;
  int lane = t & 63, w = t >> 6;
  int lr = lane & 15, lg = lane >> 4;
  int pq = t & 15;                 // p-quad: p = p0 + pq*4 + k
  int cpg = t >> 4;                // c-pair group 0..15

  const float* xb = x + (size_t)b * 256 * 4096;
  const unsigned short* wqf = wq_fl + (size_t)(ot * 4 + w) * 4096 + lane * 8;

  f32x4 acc[4];
  f32x4 z = {0.f, 0.f, 0.f, 0.f};
#pragma unroll
  for (int i = 0; i < 4; ++i) acc[i] = z;
  f32x4 sacc = z;

#define STAGE_CHUNK(buf, c0)                                                   \
  {                                                                            \
    int cb = (c0) + cpg * 2;                                                   \
    f32x4 xa = *(const f32x4*)&xb[(size_t)cb * 4096 + p0 + pq * 4];            \
    f32x4 xc = *(const f32x4*)&xb[(size_t)(cb + 1) * 4096 + p0 + pq * 4];      \
    float ga = g[cb], gc = g[cb + 1];                                          \
    int cloc = cpg * 2;                                                        \
    _Pragma("unroll")                                                          \
    for (int k = 0; k < 4; ++k) {                                              \
      sacc[k] += xa[k] * xa[k] + xc[k] * xc[k];                                \
      *(unsigned int*)&xnT[buf][swz40(pq * 4 + k, cloc)] =                     \
          pkc(xa[k] * ga, xc[k] * gc);                                         \
    }                                                                          \
  }

  STAGE_CHUNK(0, 0)
  __syncthreads();

  for (int cc = 0; cc < 8; ++cc) {
    int cur = cc & 1;
    if (cc < 7) STAGE_CHUNK(cur ^ 1, (cc + 1) * 32)
    short8 af = mk8(wqf + cc * 512);
#pragma unroll
    for (int pt16 = 0; pt16 < 4; ++pt16) {
      short8 bf = mk8(&xnT[cur][swz40(pt16 * 16 + lr, lg * 8)]);
      acc[pt16] = MFMA16(af, bf, acc[pt16]);
    }
    __syncthreads();
  }
#undef STAGE_CHUNK

#pragma unroll
  for (int k = 0; k < 4; ++k) sqv[cpg][pq * 4 + k] = sacc[k];
  __syncthreads();
  if (t < 64) {
    float tot = 0.f;
#pragma unroll
    for (int r = 0; r < 16; ++r) tot += sqv[r][t];
    rl[t] = rsqrtf(tot * (1.0f / 256.0f) + 1e-12f);
  }
  __syncthreads();

  const float cexp = 0.25505654427102996f;   // 32^-0.5 * log2(e), folded into K
  int obase = o0 + w * 16 + lg * 4;          // multiple of 4
  if (obase < 128) {
    int h = obase >> 5, d0 = obase & 31;
    unsigned short* dst = qbuf + ((size_t)(b * 4 + h) * 4096) * 32;
#pragma unroll
    for (int pt16 = 0; pt16 < 4; ++pt16) {
      int p = p0 + pt16 * 16 + lr;
      float rr = rl[pt16 * 16 + lr];
      unsigned int u0 = pk2(acc[pt16][0] * rr, acc[pt16][1] * rr);
      unsigned int u1 = pk2(acc[pt16][2] * rr, acc[pt16][3] * rr);
      uint2 uu = {u0, u1};
      *(uint2*)(dst + (size_t)p * 32 + d0) = uu;
    }
  } else if (obase < 256) {
    int oh = obase - 128;
    int h = oh >> 5, d0 = oh & 31;
    int frag = d0 >> 4, hi = (d0 >> 3) & 1, i0 = d0 & 7;
    unsigned short* dst = kbuf + (size_t)(b * 4 + h) * 131072
                         + frag * 512 + hi * 256 + i0;
#pragma unroll
    for (int pt16 = 0; pt16 < 4; ++pt16) {
      int jj = p0 + pt16 * 16 + lr;
      float rr = rl[pt16 * 16 + lr] * cexp;
      int jtile = jj >> 5, j31 = jj & 31;
      uint2 uu = {pk2(acc[pt16][0] * rr, acc[pt16][1] * rr),
                  pk2(acc[pt16][2] * rr, acc[pt16][3] * rr)};
      *(uint2*)(dst + (size_t)jtile * 1024 + j31 * 8) = uu;
    }
  } else {
    int oh = obase - 256;
    int h = oh >> 5, d0 = oh & 31;
    unsigned short* dst = vbuf + (size_t)(b * 4 + h) * 131072;
    int sl = (lr & 3) | ((lr & 4) << 1) | ((lr & 8) >> 1);
#pragma unroll
    for (int pt16 = 0; pt16 < 4; ++pt16) {
      int jj = p0 + pt16 * 16 + sl;
      float rr = rl[pt16 * 16 + lr];
      int jtile = jj >> 5, j5 = jj & 31;
      int frag = j5 >> 4, hi = (j5 >> 3) & 1, i = j5 & 7;
      size_t base = (size_t)jtile * 1024 + frag * 512 + hi * 256 + i;
#pragma unroll
      for (int r = 0; r < 4; ++r)
        dst[base + (d0 + r) * 8] = f2bf(acc[pt16][r] * rr);
    }
  }
}

// ---------------- kernel 2: flash attention (r19 loop + ones-MFMA lsum) ----------------
// lsum accumulated on the MFMA pipe via A=ones (removes 16 VALU adds/tile and
// the end shuffle: all lsacc regs hold the full row total for q = lane&31).
__global__ __launch_bounds__(256, 4) void k_attn(const unsigned short* __restrict__ qbuf,
                                                 const unsigned short* __restrict__ kbuf,
                                                 const unsigned short* __restrict__ vbuf,
                                                 unsigned short* __restrict__ attno) {
  __shared__ float Ol[3][16][64];   // partner O partials (jq 1..3)
  __shared__ float Ll[3][64];       // partner lsum

  int bid = blockIdx.x;
  int wid = ((bid & 7) << 8) | (bid >> 3);   // XCD-contiguous (2048 % 8 == 0)
  int qg = wid & 127, bh = wid >> 7;
  int t = threadIdx.x, lane = t & 63, jq = t >> 6;
  int l31 = lane & 31, hi = lane >> 5;

  const unsigned short* qgp = qbuf + (size_t)bh * 4096 * 32;
  const unsigned short* kt = kbuf + (size_t)bh * 131072;   // uniform (SGPR)
  const unsigned short* vt = vbuf + (size_t)bh * 131072;   // uniform (SGPR)

  int qrow = qg * 32 + l31;
  short8 qf0 = mk8(qgp + (size_t)qrow * 32 + hi * 8);
  short8 qf1 = mk8(qgp + (size_t)qrow * 32 + 16 + hi * 8);

  unsigned int one2 = 0x3F803F80u;           // bf16(1.0) x2
  uint4v ov = {one2, one2, one2, one2};
  short8 onesf = __builtin_bit_cast(short8, ov);

  const f32x16 z16 = zero16();
  f32x16 oacc = zero16();
  f32x16 lsacc = zero16();

  unsigned int koff = (unsigned int)(jq * 32) * 1024u + (unsigned int)lane * 8u;

  short8 kf0 = mk8(kt + koff), kf1 = mk8(kt + koff + 512);
  short8 vf0 = mk8(vt + koff), vf1 = mk8(vt + koff + 512);

  for (int it = 0; it < 32; ++it) {          // 32 tiles x 32 j = 1024 j
    __builtin_amdgcn_s_setprio(1);
    f32x16 s = MFMA32(kf0, qf0, z16);
    s = MFMA32(kf1, qf1, s);
    __builtin_amdgcn_s_setprio(0);

    koff += 1024;                            // advance to tile it+1
    kf0 = mk8(kt + koff);                    // reload K (dead on last; mapped ws)
    kf1 = mk8(kt + koff + 512);

    float p[16];
#pragma unroll
    for (int i = 0; i < 16; ++i) p[i] = __builtin_amdgcn_exp2f(s[i]);

    uint4v u0 = {pkc(p[0], p[1]), pkc(p[2], p[3]), pkc(p[4], p[5]), pkc(p[6], p[7])};
    uint4v u1 = {pkc(p[8], p[9]), pkc(p[10], p[11]), pkc(p[12], p[13]), pkc(p[14], p[15])};
    short8 pf0 = __builtin_bit_cast(short8, u0);
    short8 pf1 = __builtin_bit_cast(short8, u1);

    __builtin_amdgcn_s_setprio(1);
    lsacc = MFMA32(onesf, pf0, lsacc);       // row-sums of rounded P (A=ones)
    lsacc = MFMA32(onesf, pf1, lsacc);
    oacc = MFMA32(vf0, pf0, oacc);
    oacc = MFMA32(vf1, pf1, oacc);
    __builtin_amdgcn_s_setprio(0);

    vf0 = mk8(vt + koff);                    // reload V at same (advanced) offset
    vf1 = mk8(vt + koff + 512);
  }

  float lsum = lsacc[0];   // full row total for this j-quarter (q = lane&31)

  if (jq > 0) {
#pragma unroll
    for (int i = 0; i < 16; ++i) Ol[jq - 1][i][lane] = oacc[i];
    Ll[jq - 1][lane] = lsum;
  }
  __syncthreads();
  if (jq == 0) {
    float rinv = 1.0f / (lsum + Ll[0][lane] + Ll[1][lane] + Ll[2][lane]);

    int b = bh >> 2, h = bh & 3;
    // fragment-linear epilogue: ptile = qrow>>4, cchunk = h
    unsigned short* ob = attno + (((size_t)(b * 256 + (qrow >> 4)) * 4 + h) * 512)
                         + (qrow & 15) * 8;
#pragma unroll
    for (int r2 = 0; r2 < 8; ++r2) {
      int reg = r2 * 2;
      int dv = (reg & 3) + 8 * (reg >> 2) + 4 * hi;
      float v0 = (oacc[reg] + Ol[0][reg][lane] + Ol[1][reg][lane] + Ol[2][reg][lane]) * rinv;
      float v1 = (oacc[reg + 1] + Ol[0][reg + 1][lane] + Ol[1][reg + 1][lane] + Ol[2][reg + 1][lane]) * rinv;
      *(unsigned int*)(ob + (dv >> 3) * 128 + (dv & 7)) = pk2(v0, v1);
    }
  }
}

// ---------------- kernel 3: output projection + bias, fragment-linear ----------------
__global__ __launch_bounds__(256) void k_out(const unsigned short* __restrict__ attno,
                                             const unsigned short* __restrict__ wo_fl,
                                             const float* __restrict__ bo,
                                             float* __restrict__ out) {
  int bid = blockIdx.x;            // 1024 = 4b * 4cog * 64pt
  int b = bid >> 8;
  int rem = bid & 255;
  int cog = rem >> 6;
  int p0 = (rem & 63) * 64;
  int co0 = cog * 64;
  int t = threadIdx.x, lane = t & 63, w = t >> 6;
  int lr = lane & 15, lg = lane >> 4;

  f32x4 z = {0.f, 0.f, 0.f, 0.f};
  f32x4 acc[4];
#pragma unroll
  for (int j = 0; j < 4; ++j) acc[j] = z;

  const unsigned short* wof = wo_fl + (size_t)(cog * 4 + w) * 2048 + lane * 8;
  const unsigned short* atf = attno + (size_t)(b * 256 + (p0 >> 4)) * 2048 + lane * 8;

#pragma unroll
  for (int cch = 0; cch < 4; ++cch) {
    short8 afr = mk8(wof + cch * 512);
#pragma unroll
    for (int pt16 = 0; pt16 < 4; ++pt16) {
      short8 bfr = mk8(atf + (size_t)pt16 * 2048 + cch * 512);
      acc[pt16] = MFMA16(afr, bfr, acc[pt16]);
    }
  }

#pragma unroll
  for (int pt16 = 0; pt16 < 4; ++pt16) {
#pragma unroll
    for (int r = 0; r < 4; ++r) {
      int co = co0 + w * 16 + lg * 4 + r;
      int p = p0 + pt16 * 16 + lr;
      out[((size_t)b * 256 + co) * 4096 + p] = acc[pt16][r] + bo[co];
    }
  }
}

extern "C" void kernel_launch(void* const* d_in, const int* in_sizes, int n_in,
                              void* d_out, int out_size, void* d_ws, size_t ws_size,
                              hipStream_t stream) {
  const float* x = (const float*)d_in[0];
  const float* g = (const float*)d_in[1];
  const float* wq = (const float*)d_in[2];
  const float* wo = (const float*)d_in[3];
  const float* bo = (const float*)d_in[4];
  float* out = (float*)d_out;

  char* ws = (char*)d_ws;
  unsigned short* wq_fl = (unsigned short*)(ws + 65536);     // 196608 B
  unsigned short* wo_fl = (unsigned short*)(ws + 262144);    // 65536 B
  unsigned short* qbuf = (unsigned short*)(ws + 327680);     // 4 MiB
  unsigned short* kbuf = (unsigned short*)(ws + 4521984);    // 4 MiB
  unsigned short* vbuf = (unsigned short*)(ws + 8716288);    // 4 MiB
  unsigned short* attno = (unsigned short*)(ws + 12910592);  // 4 MiB

  k_prep<<<dim3(384), dim3(256), 0, stream>>>(wq, wo, wq_fl, wo_fl);
  k_qkv<<<dim3(1536), dim3(256), 0, stream>>>(x, g, wq_fl, qbuf, kbuf, vbuf);
  k_attn<<<dim3(2048), dim3(256), 0, stream>>>(qbuf, kbuf, vbuf, attno);
  k_out<<<dim3(1024), dim3(256), 0, stream>>>(attno, wo_fl, bo, out);
}

// Round 23
// 88.017 us; speedup vs baseline: 1.0505x; 1.0505x over previous
//
#include <hip/hip_runtime.h>
#include <hip/hip_bf16.h>
#include <stdint.h>
#include <stddef.h>

typedef __attribute__((ext_vector_type(8))) short short8;
typedef __attribute__((ext_vector_type(4))) float f32x4;
typedef __attribute__((ext_vector_type(16))) float f32x16;
typedef __attribute__((ext_vector_type(4))) unsigned int uint4v;

#define MFMA16(a, b, c) __builtin_amdgcn_mfma_f32_16x16x32_bf16((a), (b), (c), 0, 0, 0)
#define MFMA32(a, b, c) __builtin_amdgcn_mfma_f32_32x32x16_bf16((a), (b), (c), 0, 0, 0)

__device__ __forceinline__ unsigned short f2bf(float f) {
  unsigned int u = __builtin_bit_cast(unsigned int, f);
  u += 0x7fffu + ((u >> 16) & 1u);
  return (unsigned short)(u >> 16);
}

// validated integer RNE pack — cold paths
__device__ __forceinline__ unsigned int pk2(float lo, float hi) {
  return (unsigned int)f2bf(lo) | ((unsigned int)f2bf(hi) << 16);
}

// hot-path pack: official intrinsic -> compiler-emitted v_cvt_pk_bf16_f32
__device__ __forceinline__ unsigned int pkc(float lo, float hi) {
  __hip_bfloat162 h = __float22bfloat162_rn(make_float2(lo, hi));
  unsigned int u;
  __builtin_memcpy(&u, &h, 4);
  return u;
}

__device__ __forceinline__ short8 mk8(const unsigned short* p) {
  return *(const short8*)p;
}

__device__ __forceinline__ float redsum32(float v) {
  return v + __shfl_xor(v, 32);
}

__device__ __forceinline__ f32x16 zero16() {
  f32x16 v;
#pragma unroll
  for (int i = 0; i < 16; ++i) v[i] = 0.f;
  return v;
}

// swizzled offset into a [rows][40]-half LDS tile holding 32 data cols.
__device__ __forceinline__ int swz40(int row, int c) {
  return row * 40 + ((((c >> 3) ^ (row >> 3)) & 3) << 3) + (c & 7);
}

// ---------------- kernel 0: pack weights into A-fragment-linear bf16 ----------------
__global__ __launch_bounds__(256) void k_prep(const float* __restrict__ wq,
                                              const float* __restrict__ wo,
                                              unsigned short* __restrict__ wq_fl,
                                              unsigned short* __restrict__ wo_fl) {
  int i = blockIdx.x * 256 + threadIdx.x;
  if (i < 98304) {
    int slot = i & 7, lane = (i >> 3) & 63, cch = (i >> 9) & 7, otile = i >> 12;
    int o = otile * 16 + (lane & 15);
    int c = cch * 32 + ((lane >> 4) & 3) * 8 + slot;
    wq_fl[i] = f2bf(wq[o * 256 + c]);
  }
  if (i < 32768) {
    int slot = i & 7, lane = (i >> 3) & 63, cch = (i >> 9) & 3, cotile = i >> 11;
    int co = cotile * 16 + (lane & 15);
    int c = cch * 32 + (lane >> 4) * 8 + slot;
    wo_fl[i] = f2bf(wo[co * 128 + c]);
  }
}

// ---------------- kernel 1: fused RMSNorm + QKV GEMM ----------------
__global__ __launch_bounds__(256) void k_qkv(const float* __restrict__ x,
                                             const float* __restrict__ g,
                                             const unsigned short* __restrict__ wq_fl,
                                             unsigned short* __restrict__ qbuf,
                                             unsigned short* __restrict__ kbuf,
                                             unsigned short* __restrict__ vbuf) {
  int bid = blockIdx.x;            // 1536 = 4b * 6ot * 64pt
  int b = bid / 384;
  int rem = bid % 384;
  int ot = rem / 64;
  int pt = rem % 64;
  int o0 = ot * 64, p0 = pt * 64;

  __shared__ unsigned short xnT[2][64 * 40];
  __shared__ float sqv[16][64];
  __shared__ float rl[64];

  int t = threadIdx.x;
  int lane = t & 63, w = t >> 6;
  int lr = lane & 15, lg = lane >> 4;
  int pq = t & 15;                 // p-quad: p = p0 + pq*4 + k
  int cpg = t >> 4;                // c-pair group 0..15

  const float* xb = x + (size_t)b * 256 * 4096;
  const unsigned short* wqf = wq_fl + (size_t)(ot * 4 + w) * 4096 + lane * 8;

  f32x4 acc[4];
  f32x4 z = {0.f, 0.f, 0.f, 0.f};
#pragma unroll
  for (int i = 0; i < 4; ++i) acc[i] = z;
  f32x4 sacc = z;

#define STAGE_CHUNK(buf, c0)                                                   \
  {                                                                            \
    int cb = (c0) + cpg * 2;                                                   \
    f32x4 xa = *(const f32x4*)&xb[(size_t)cb * 4096 + p0 + pq * 4];            \
    f32x4 xc = *(const f32x4*)&xb[(size_t)(cb + 1) * 4096 + p0 + pq * 4];      \
    float ga = g[cb], gc = g[cb + 1];                                          \
    int cloc = cpg * 2;                                                        \
    _Pragma("unroll")                                                          \
    for (int k = 0; k < 4; ++k) {                                              \
      sacc[k] += xa[k] * xa[k] + xc[k] * xc[k];                                \
      *(unsigned int*)&xnT[buf][swz40(pq * 4 + k, cloc)] =                     \
          pkc(xa[k] * ga, xc[k] * gc);                                         \
    }                                                                          \
  }

  STAGE_CHUNK(0, 0)
  __syncthreads();

  for (int cc = 0; cc < 8; ++cc) {
    int cur = cc & 1;
    if (cc < 7) STAGE_CHUNK(cur ^ 1, (cc + 1) * 32)
    short8 af = mk8(wqf + cc * 512);
#pragma unroll
    for (int pt16 = 0; pt16 < 4; ++pt16) {
      short8 bf = mk8(&xnT[cur][swz40(pt16 * 16 + lr, lg * 8)]);
      acc[pt16] = MFMA16(af, bf, acc[pt16]);
    }
    __syncthreads();
  }
#undef STAGE_CHUNK

#pragma unroll
  for (int k = 0; k < 4; ++k) sqv[cpg][pq * 4 + k] = sacc[k];
  __syncthreads();
  if (t < 64) {
    float tot = 0.f;
#pragma unroll
    for (int r = 0; r < 16; ++r) tot += sqv[r][t];
    rl[t] = rsqrtf(tot * (1.0f / 256.0f) + 1e-12f);
  }
  __syncthreads();

  const float cexp = 0.25505654427102996f;   // 32^-0.5 * log2(e), folded into K
  int obase = o0 + w * 16 + lg * 4;          // multiple of 4
  if (obase < 128) {
    int h = obase >> 5, d0 = obase & 31;
    unsigned short* dst = qbuf + ((size_t)(b * 4 + h) * 4096) * 32;
#pragma unroll
    for (int pt16 = 0; pt16 < 4; ++pt16) {
      int p = p0 + pt16 * 16 + lr;
      float rr = rl[pt16 * 16 + lr];
      unsigned int u0 = pk2(acc[pt16][0] * rr, acc[pt16][1] * rr);
      unsigned int u1 = pk2(acc[pt16][2] * rr, acc[pt16][3] * rr);
      uint2 uu = {u0, u1};
      *(uint2*)(dst + (size_t)p * 32 + d0) = uu;
    }
  } else if (obase < 256) {
    int oh = obase - 128;
    int h = oh >> 5, d0 = oh & 31;
    int frag = d0 >> 4, hi = (d0 >> 3) & 1, i0 = d0 & 7;
    unsigned short* dst = kbuf + (size_t)(b * 4 + h) * 131072
                         + frag * 512 + hi * 256 + i0;
#pragma unroll
    for (int pt16 = 0; pt16 < 4; ++pt16) {
      int jj = p0 + pt16 * 16 + lr;
      float rr = rl[pt16 * 16 + lr] * cexp;
      int jtile = jj >> 5, j31 = jj & 31;
      uint2 uu = {pk2(acc[pt16][0] * rr, acc[pt16][1] * rr),
                  pk2(acc[pt16][2] * rr, acc[pt16][3] * rr)};
      *(uint2*)(dst + (size_t)jtile * 1024 + j31 * 8) = uu;
    }
  } else {
    int oh = obase - 256;
    int h = oh >> 5, d0 = oh & 31;
    unsigned short* dst = vbuf + (size_t)(b * 4 + h) * 131072;
    int sl = (lr & 3) | ((lr & 4) << 1) | ((lr & 8) >> 1);
#pragma unroll
    for (int pt16 = 0; pt16 < 4; ++pt16) {
      int jj = p0 + pt16 * 16 + sl;
      float rr = rl[pt16 * 16 + lr];
      int jtile = jj >> 5, j5 = jj & 31;
      int frag = j5 >> 4, hi = (j5 >> 3) & 1, i = j5 & 7;
      size_t base = (size_t)jtile * 1024 + frag * 512 + hi * 256 + i;
#pragma unroll
      for (int r = 0; r < 4; ++r)
        dst[base + (d0 + r) * 8] = f2bf(acc[pt16][r] * rr);
    }
  }
}

// ---------------- kernel 2: flash attention (r19/r20 best variant) ----------------
__global__ __launch_bounds__(256, 5) void k_attn(const unsigned short* __restrict__ qbuf,
                                                 const unsigned short* __restrict__ kbuf,
                                                 const unsigned short* __restrict__ vbuf,
                                                 unsigned short* __restrict__ attno) {
  __shared__ float Ol[3][16][64];   // partner O partials (jq 1..3)
  __shared__ float Ll[3][64];       // partner lsum

  int bid = blockIdx.x;
  int wid = ((bid & 7) << 8) | (bid >> 3);   // XCD-contiguous (2048 % 8 == 0)
  int qg = wid & 127, bh = wid >> 7;
  int t = threadIdx.x, lane = t & 63, jq = t >> 6;
  int l31 = lane & 31, hi = lane >> 5;

  const unsigned short* qgp = qbuf + (size_t)bh * 4096 * 32;
  const unsigned short* kt = kbuf + (size_t)bh * 131072;   // uniform (SGPR)
  const unsigned short* vt = vbuf + (size_t)bh * 131072;   // uniform (SGPR)

  int qrow = qg * 32 + l31;
  short8 qf0 = mk8(qgp + (size_t)qrow * 32 + hi * 8);
  short8 qf1 = mk8(qgp + (size_t)qrow * 32 + 16 + hi * 8);

  const f32x16 z16 = zero16();
  f32x16 oacc = zero16();
  float lsum = 0.f;

  unsigned int koff = (unsigned int)(jq * 32) * 1024u + (unsigned int)lane * 8u;

  short8 kf0 = mk8(kt + koff), kf1 = mk8(kt + koff + 512);
  short8 vf0 = mk8(vt + koff), vf1 = mk8(vt + koff + 512);

  for (int it = 0; it < 32; ++it) {          // 32 tiles x 32 j = 1024 j
    __builtin_amdgcn_s_setprio(1);
    f32x16 s = MFMA32(kf0, qf0, z16);
    s = MFMA32(kf1, qf1, s);
    __builtin_amdgcn_s_setprio(0);

    koff += 1024;                            // advance to tile it+1
    kf0 = mk8(kt + koff);                    // reload K (dead on last; mapped ws)
    kf1 = mk8(kt + koff + 512);

    float p[16];
#pragma unroll
    for (int i = 0; i < 16; ++i) p[i] = __builtin_amdgcn_exp2f(s[i]);

    float s0 = ((p[0] + p[1]) + (p[2] + p[3])) + ((p[4] + p[5]) + (p[6] + p[7]));
    float s1 = ((p[8] + p[9]) + (p[10] + p[11])) + ((p[12] + p[13]) + (p[14] + p[15]));
    lsum += s0 + s1;

    uint4v u0 = {pkc(p[0], p[1]), pkc(p[2], p[3]), pkc(p[4], p[5]), pkc(p[6], p[7])};
    uint4v u1 = {pkc(p[8], p[9]), pkc(p[10], p[11]), pkc(p[12], p[13]), pkc(p[14], p[15])};
    short8 pf0 = __builtin_bit_cast(short8, u0);
    short8 pf1 = __builtin_bit_cast(short8, u1);

    __builtin_amdgcn_s_setprio(1);
    oacc = MFMA32(vf0, pf0, oacc);
    oacc = MFMA32(vf1, pf1, oacc);
    __builtin_amdgcn_s_setprio(0);

    vf0 = mk8(vt + koff);                    // reload V at same (advanced) offset
    vf1 = mk8(vt + koff + 512);
  }

  lsum = redsum32(lsum);   // pair row-total for this j-quarter

  if (jq > 0) {
#pragma unroll
    for (int i = 0; i < 16; ++i) Ol[jq - 1][i][lane] = oacc[i];
    Ll[jq - 1][lane] = lsum;
  }
  __syncthreads();
  if (jq == 0) {
    float rinv = 1.0f / (lsum + Ll[0][lane] + Ll[1][lane] + Ll[2][lane]);

    int b = bh >> 2, h = bh & 3;
    // fragment-linear epilogue: ptile = qrow>>4, cchunk = h
    unsigned short* ob = attno + (((size_t)(b * 256 + (qrow >> 4)) * 4 + h) * 512)
                         + (qrow & 15) * 8;
#pragma unroll
    for (int r2 = 0; r2 < 8; ++r2) {
      int reg = r2 * 2;
      int dv = (reg & 3) + 8 * (reg >> 2) + 4 * hi;
      float v0 = (oacc[reg] + Ol[0][reg][lane] + Ol[1][reg][lane] + Ol[2][reg][lane]) * rinv;
      float v1 = (oacc[reg + 1] + Ol[0][reg + 1][lane] + Ol[1][reg + 1][lane] + Ol[2][reg + 1][lane]) * rinv;
      *(unsigned int*)(ob + (dv >> 3) * 128 + (dv & 7)) = pk2(v0, v1);
    }
  }
}

// ---------------- kernel 3: output projection + bias, fragment-linear ----------------
__global__ __launch_bounds__(256) void k_out(const unsigned short* __restrict__ attno,
                                             const unsigned short* __restrict__ wo_fl,
                                             const float* __restrict__ bo,
                                             float* __restrict__ out) {
  int bid = blockIdx.x;            // 1024 = 4b * 4cog * 64pt
  int b = bid >> 8;
  int rem = bid & 255;
  int cog = rem >> 6;
  int p0 = (rem & 63) * 64;
  int co0 = cog * 64;
  int t = threadIdx.x, lane = t & 63, w = t >> 6;
  int lr = lane & 15, lg = lane >> 4;

  f32x4 z = {0.f, 0.f, 0.f, 0.f};
  f32x4 acc[4];
#pragma unroll
  for (int j = 0; j < 4; ++j) acc[j] = z;

  const unsigned short* wof = wo_fl + (size_t)(cog * 4 + w) * 2048 + lane * 8;
  const unsigned short* atf = attno + (size_t)(b * 256 + (p0 >> 4)) * 2048 + lane * 8;

#pragma unroll
  for (int cch = 0; cch < 4; ++cch) {
    short8 afr = mk8(wof + cch * 512);
#pragma unroll
    for (int pt16 = 0; pt16 < 4; ++pt16) {
      short8 bfr = mk8(atf + (size_t)pt16 * 2048 + cch * 512);
      acc[pt16] = MFMA16(afr, bfr, acc[pt16]);
    }
  }

#pragma unroll
  for (int pt16 = 0; pt16 < 4; ++pt16) {
#pragma unroll
    for (int r = 0; r < 4; ++r) {
      int co = co0 + w * 16 + lg * 4 + r;
      int p = p0 + pt16 * 16 + lr;
      out[((size_t)b * 256 + co) * 4096 + p] = acc[pt16][r] + bo[co];
    }
  }
}

extern "C" void kernel_launch(void* const* d_in, const int* in_sizes, int n_in,
                              void* d_out, int out_size, void* d_ws, size_t ws_size,
                              hipStream_t stream) {
  const float* x = (const float*)d_in[0];
  const float* g = (const float*)d_in[1];
  const float* wq = (const float*)d_in[2];
  const float* wo = (const float*)d_in[3];
  const float* bo = (const float*)d_in[4];
  float* out = (float*)d_out;

  char* ws = (char*)d_ws;
  unsigned short* wq_fl = (unsigned short*)(ws + 65536);     // 196608 B
  unsigned short* wo_fl = (unsigned short*)(ws + 262144);    // 65536 B
  unsigned short* qbuf = (unsigned short*)(ws + 327680);     // 4 MiB
  unsigned short* kbuf = (unsigned short*)(ws + 4521984);    // 4 MiB
  unsigned short* vbuf = (unsigned short*)(ws + 8716288);    // 4 MiB
  unsigned short* attno = (unsigned short*)(ws + 12910592);  // 4 MiB

  k_prep<<<dim3(384), dim3(256), 0, stream>>>(wq, wo, wq_fl, wo_fl);
  k_qkv<<<dim3(1536), dim3(256), 0, stream>>>(x, g, wq_fl, qbuf, kbuf, vbuf);
  k_attn<<<dim3(2048), dim3(256), 0, stream>>>(qbuf, kbuf, vbuf, attno);
  k_out<<<dim3(1024), dim3(256), 0, stream>>>(attno, wo_fl, bo, out);
}